// Round 1
// baseline (903.816 us; speedup 1.0000x reference)
//
#include <hip/hip_runtime.h>
#include <math.h>

#define LQ 4096
#define DD 512
#define NH 8
#define HS 64
#define HALF 32

// workspace offsets (in floats)
#define OFF_Q   0
#define OFF_K   (NH*LQ*HS)
#define OFF_V   (2*NH*LQ*HS)
#define OFF_RET (3*NH*LQ*HS)
#define OFF_GATE (3*NH*LQ*HS + LQ*DD)
#define OFF_TAB (3*NH*LQ*HS + 2*LQ*DD)
// tab: 4 tables of LQ*HALF floats (cos*s_q, sin*s_q, cos/s, sin/s)

// ---------------- xPos tables (double precision, tiny) ----------------
__global__ __launch_bounds__(256) void k_tables(float* __restrict__ tab) {
    int idx = blockIdx.x * 256 + threadIdx.x;   // LQ*HALF = 131072
    if (idx >= LQ * HALF) return;
    int l = idx >> 5;
    int i = idx & 31;
    double sv  = (2.0 * i + 0.4 * (double)HS) / (1.4 * (double)HS);
    double s   = pow(sv, (double)l / 512.0);
    double invf = pow(10000.0, -(double)i / (double)HALF);
    double th  = (double)l * invf;
    double c = cos(th), sn = sin(th);
    tab[idx]                 = (float)(c * s);
    tab[LQ*HALF + idx]       = (float)(sn * s);
    tab[2*LQ*HALF + idx]     = (float)(c / s);
    tab[3*LQ*HALF + idx]     = (float)(sn / s);
}

// ---------------- QKV projection + xPos ----------------
// grid (LQ/64, NH), block 256.  q/k/v layout: [h][l][hs]
__global__ __launch_bounds__(256) void k_qkv(
    const float* __restrict__ X,
    const float* __restrict__ Wq, const float* __restrict__ Wk, const float* __restrict__ Wv,
    const float* __restrict__ tab,
    float* __restrict__ q, float* __restrict__ k, float* __restrict__ v) {
    __shared__ float Xs[64][64];
    __shared__ float Ws0[64][64], Ws1[64][64], Ws2[64][64];
    const int t = threadIdx.x;
    const int l0 = blockIdx.x * 64;
    const int h = blockIdx.y;
    const int col = t & 63, w = t >> 6;

    const float* WqH = Wq + (size_t)h * DD * HS;
    const float* WkH = Wk + (size_t)h * DD * HS;
    const float* WvH = Wv + (size_t)h * DD * HS;

    float aq[16], ak[16], av[16];
#pragma unroll
    for (int j = 0; j < 16; ++j) { aq[j] = 0.f; ak[j] = 0.f; av[j] = 0.f; }

    for (int kt = 0; kt < 8; ++kt) {
#pragma unroll
        for (int m = 0; m < 16; ++m) {
            int e = t + m * 256;
            int r = e >> 6, c = e & 63;
            Xs[r][c]  = X[(size_t)(l0 + r) * DD + kt * 64 + c];
            Ws0[r][c] = WqH[(size_t)(kt * 64 + r) * HS + c];
            Ws1[r][c] = WkH[(size_t)(kt * 64 + r) * HS + c];
            Ws2[r][c] = WvH[(size_t)(kt * 64 + r) * HS + c];
        }
        __syncthreads();
        for (int kk = 0; kk < 64; ++kk) {
            float wq = Ws0[kk][col], wk = Ws1[kk][col], wv = Ws2[kk][col];
#pragma unroll
            for (int j = 0; j < 16; ++j) {
                float x = Xs[w * 16 + j][kk];
                aq[j] = fmaf(x, wq, aq[j]);
                ak[j] = fmaf(x, wk, ak[j]);
                av[j] = fmaf(x, wv, av[j]);
            }
        }
        __syncthreads();
    }

    // xPos rotation: pairs (2i, 2i+1); partner value lives in lane col^1
    const int i = col >> 1;
#pragma unroll
    for (int j = 0; j < 16; ++j) {
        int r = w * 16 + j;
        int pos = l0 + r;
        float cq = tab[(size_t)pos * HALF + i];
        float sq = tab[LQ*HALF + (size_t)pos * HALF + i];
        float ck = tab[2*LQ*HALF + (size_t)pos * HALF + i];
        float sk = tab[3*LQ*HALF + (size_t)pos * HALF + i];
        float pq = __shfl_xor(aq[j], 1);
        float pk = __shfl_xor(ak[j], 1);
        float rq = (col & 1) ? pq : -pq;   // rot[2i]=-x[2i+1], rot[2i+1]=x[2i]
        float rk = (col & 1) ? pk : -pk;
        size_t o = ((size_t)h * LQ + pos) * HS + col;
        q[o] = fmaf(aq[j], cq, rq * sq);
        k[o] = fmaf(ak[j], ck, rk * sk);
        v[o] = av[j];
    }
}

// ---------------- retention: flash-style causal with decay ----------------
// grid (LQ/64, NH), block 256. ret layout: [l][h*HS + c] (i.e. L x 512)
__global__ __launch_bounds__(256) void k_ret(
    const float* __restrict__ q, const float* __restrict__ k, const float* __restrict__ v,
    float* __restrict__ ret) {
    __shared__ float Qs[64][65];
    __shared__ float KSs[64][65];   // K tile, reused as S tile
    __shared__ float Vs[64][64];
    const int t = threadIdx.x;
    // load-balance: pair light (low qb) and heavy (high qb) blocks
    const int bx = blockIdx.x;
    const int qb = (bx & 1) ? (63 - (bx >> 1)) : (bx >> 1);
    const int h = blockIdx.y;
    const int l0 = qb * 64;
    const int tr = t >> 4, tc = t & 15;

    float lgf;
    {
        double lg = log(1.0/32.0) + (double)h * (log(1.0/512.0) - log(1.0/32.0)) / 7.0;
        double gamma = 1.0 - exp(lg);
        lgf = (float)(log(gamma) * 1.4426950408889634);  // log2(gamma)
    }

#pragma unroll
    for (int m = 0; m < 16; ++m) {
        int e = t + m * 256;
        int r = e >> 6, c = e & 63;
        Qs[r][c] = q[((size_t)h * LQ + l0 + r) * HS + c];
    }

    float o[4][4];
#pragma unroll
    for (int i = 0; i < 4; ++i)
#pragma unroll
        for (int j = 0; j < 4; ++j) o[i][j] = 0.f;

    for (int kb = 0; kb <= qb; ++kb) {
#pragma unroll
        for (int m = 0; m < 16; ++m) {
            int e = t + m * 256;
            int r = e >> 6, c = e & 63;
            KSs[r][c] = k[((size_t)h * LQ + kb * 64 + r) * HS + c];
            Vs[r][c]  = v[((size_t)h * LQ + kb * 64 + r) * HS + c];
        }
        __syncthreads();

        // S = Q K^T for this thread's 4x4 sub-tile
        float s[4][4];
#pragma unroll
        for (int i = 0; i < 4; ++i)
#pragma unroll
            for (int j = 0; j < 4; ++j) s[i][j] = 0.f;
        for (int d = 0; d < 64; ++d) {
            float qv[4], kv[4];
#pragma unroll
            for (int i = 0; i < 4; ++i) qv[i] = Qs[tr * 4 + i][d];
#pragma unroll
            for (int j = 0; j < 4; ++j) kv[j] = KSs[tc * 4 + j][d];
#pragma unroll
            for (int i = 0; i < 4; ++i)
#pragma unroll
                for (int j = 0; j < 4; ++j) s[i][j] = fmaf(qv[i], kv[j], s[i][j]);
        }
        __syncthreads();   // done reading K tile

        // decay mask and store S into (reused) LDS
        const int base = l0 - kb * 64;
#pragma unroll
        for (int i = 0; i < 4; ++i) {
#pragma unroll
            for (int j = 0; j < 4; ++j) {
                int di = base + (tr * 4 + i) - (tc * 4 + j);
                float wgt = (di < 0) ? 0.f : exp2f(lgf * (float)di);
                KSs[tr * 4 + i][tc * 4 + j] = s[i][j] * wgt;
            }
        }
        __syncthreads();

        // O += S V
        for (int c = 0; c < 64; ++c) {
            float sv[4], vv[4];
#pragma unroll
            for (int i = 0; i < 4; ++i) sv[i] = KSs[tr * 4 + i][c];
#pragma unroll
            for (int j = 0; j < 4; ++j) vv[j] = Vs[c][tc * 4 + j];
#pragma unroll
            for (int i = 0; i < 4; ++i)
#pragma unroll
                for (int j = 0; j < 4; ++j) o[i][j] = fmaf(sv[i], vv[j], o[i][j]);
        }
        __syncthreads();   // before next tile overwrite
    }

#pragma unroll
    for (int i = 0; i < 4; ++i)
#pragma unroll
        for (int j = 0; j < 4; ++j)
            ret[(size_t)(l0 + tr * 4 + i) * DD + h * HS + tc * 4 + j] = o[i][j];
}

// ---------------- generic 64x64-tiled matmul (LxD @ DxD), optional silu ----------------
// grid (LQ/64, DD/64), block 256
__global__ __launch_bounds__(256) void k_mm(
    const float* __restrict__ A, const float* __restrict__ W,
    float* __restrict__ out, int do_silu) {
    __shared__ float As[64][65];
    __shared__ float Ws[64][64];
    const int t = threadIdx.x;
    const int l0 = blockIdx.x * 64;
    const int c0 = blockIdx.y * 64;
    const int tr = t >> 4, tc = t & 15;

    float acc[4][4];
#pragma unroll
    for (int i = 0; i < 4; ++i)
#pragma unroll
        for (int j = 0; j < 4; ++j) acc[i][j] = 0.f;

    for (int kt = 0; kt < 8; ++kt) {
#pragma unroll
        for (int m = 0; m < 16; ++m) {
            int e = t + m * 256;
            int r = e >> 6, c = e & 63;
            As[r][c] = A[(size_t)(l0 + r) * DD + kt * 64 + c];
            Ws[r][c] = W[(size_t)(kt * 64 + r) * DD + c0 + c];
        }
        __syncthreads();
        for (int kk = 0; kk < 64; ++kk) {
            float xv[4], wv[4];
#pragma unroll
            for (int i = 0; i < 4; ++i) xv[i] = As[tr * 4 + i][kk];
#pragma unroll
            for (int j = 0; j < 4; ++j) wv[j] = Ws[kk][tc * 4 + j];
#pragma unroll
            for (int i = 0; i < 4; ++i)
#pragma unroll
                for (int j = 0; j < 4; ++j) acc[i][j] = fmaf(xv[i], wv[j], acc[i][j]);
        }
        __syncthreads();
    }

#pragma unroll
    for (int i = 0; i < 4; ++i) {
#pragma unroll
        for (int j = 0; j < 4; ++j) {
            float a = acc[i][j];
            if (do_silu) a = a / (1.f + expf(-a));
            out[(size_t)(l0 + tr * 4 + i) * DD + c0 + tc * 4 + j] = a;
        }
    }
}

// ---------------- GroupNorm (per l,h over 64 channels) * gate, in place on ret ----------------
// grid LQ*NH/4, block 256 (one wave per group)
__global__ __launch_bounds__(256) void k_gn(
    float* __restrict__ ret, const float* __restrict__ gate,
    const float* __restrict__ gw, const float* __restrict__ gb) {
    const int t = threadIdx.x;
    const int w = t >> 6;
    const int lane = t & 63;
    const int grp = blockIdx.x * 4 + w;   // LQ*NH groups
    const int l = grp >> 3;
    const int h = grp & 7;
    const size_t idx = (size_t)l * DD + h * HS + lane;

    float val = ret[idx];
    float s = val;
#pragma unroll
    for (int off = 1; off < 64; off <<= 1) s += __shfl_xor(s, off);
    float mean = s * (1.f / 64.f);
    float d = val - mean;
    float ss = d * d;
#pragma unroll
    for (int off = 1; off < 64; off <<= 1) ss += __shfl_xor(ss, off);
    float var = ss * (1.f / 64.f);
    float g = d * rsqrtf(var + 1e-5f);
    g = fmaf(g, gw[h * HS + lane], gb[h * HS + lane]);
    ret[idx] = g * gate[idx];
}

extern "C" void kernel_launch(void* const* d_in, const int* in_sizes, int n_in,
                              void* d_out, int out_size, void* d_ws, size_t ws_size,
                              hipStream_t stream) {
    const float* X   = (const float*)d_in[0];
    const float* W_Q = (const float*)d_in[1];
    const float* W_K = (const float*)d_in[2];
    const float* W_V = (const float*)d_in[3];
    const float* W_G = (const float*)d_in[4];
    const float* W_O = (const float*)d_in[5];
    const float* gnw = (const float*)d_in[6];
    const float* gnb = (const float*)d_in[7];

    float* ws   = (float*)d_ws;
    float* q    = ws + OFF_Q;
    float* k    = ws + OFF_K;
    float* v    = ws + OFF_V;
    float* ret  = ws + OFF_RET;
    float* gate = ws + OFF_GATE;
    float* tab  = ws + OFF_TAB;
    float* out  = (float*)d_out;

    k_tables<<<(LQ * HALF + 255) / 256, 256, 0, stream>>>(tab);
    k_qkv<<<dim3(LQ / 64, NH), 256, 0, stream>>>(X, W_Q, W_K, W_V, tab, q, k, v);
    k_ret<<<dim3(LQ / 64, NH), 256, 0, stream>>>(q, k, v, ret);
    k_mm<<<dim3(LQ / 64, DD / 64), 256, 0, stream>>>(X, W_G, gate, 1);
    k_gn<<<(LQ * NH) / 4, 256, 0, stream>>>(ret, gate, gnw, gnb);
    k_mm<<<dim3(LQ / 64, DD / 64), 256, 0, stream>>>(ret, W_O, out, 0);
}

// Round 2
// 389.401 us; speedup vs baseline: 2.3210x; 2.3210x over previous
//
#include <hip/hip_runtime.h>
#include <math.h>

#define LQ 4096
#define DD 512
#define NH 8
#define HS 64
#define HALF 32

typedef unsigned short u16;
typedef __attribute__((ext_vector_type(8)))  short s8v;   // 8 x bf16 (MFMA A/B frag)
typedef __attribute__((ext_vector_type(4)))  float f4v;
typedef __attribute__((ext_vector_type(16))) float f16v;  // 32x32 MFMA C/D

// workspace offsets (in floats)
#define WS_Q    0
#define WS_KH   2097152
#define WS_KL   3145728
#define WS_VT   4194304
#define WS_RET  5242880
#define WS_GATE 7340032
#define WS_TAB  9437184

__device__ inline u16 f2bf(float x) {
    unsigned int u = __float_as_uint(x);
    return (u16)((u + 0x7fffu + ((u >> 16) & 1u)) >> 16);
}
__device__ inline float bf2f(u16 h) { return __uint_as_float(((unsigned int)h) << 16); }

// ---------------- xPos tables (double precision, tiny) ----------------
__global__ __launch_bounds__(256) void k_tables(float* __restrict__ tab) {
    int idx = blockIdx.x * 256 + threadIdx.x;   // LQ*HALF = 131072
    if (idx >= LQ * HALF) return;
    int l = idx >> 5;
    int i = idx & 31;
    double sv  = (2.0 * i + 0.4 * (double)HS) / (1.4 * (double)HS);
    double s   = pow(sv, (double)l / 512.0);
    double invf = pow(10000.0, -(double)i / (double)HALF);
    double th  = (double)l * invf;
    double c = cos(th), sn = sin(th);
    tab[idx]                 = (float)(c * s);
    tab[LQ*HALF + idx]       = (float)(sn * s);
    tab[2*LQ*HALF + idx]     = (float)(c / s);
    tab[3*LQ*HALF + idx]     = (float)(sn / s);
}

// ---------------- QKV projection + xPos ----------------
// grid (LQ/64, NH), block 256.
// outputs: q fp32 [h][l][64]; k_hi,k_lo bf16 [h][l][64]; vt bf16 [h][64][l]
__global__ __launch_bounds__(256) void k_qkv(
    const float* __restrict__ X,
    const float* __restrict__ Wq, const float* __restrict__ Wk, const float* __restrict__ Wv,
    const float* __restrict__ tab,
    float* __restrict__ q, u16* __restrict__ kh, u16* __restrict__ kl, u16* __restrict__ vt) {
    __shared__ float smem[4 * 4096];
    float* Xs = smem;
    float* W0 = smem + 4096;
    float* W1 = smem + 8192;
    float* W2 = smem + 12288;
    const int t = threadIdx.x;
    const int l0 = blockIdx.x * 64;
    const int h = blockIdx.y;
    const int col = t & 63, w = t >> 6;

    const float* WqH = Wq + (size_t)h * DD * HS;
    const float* WkH = Wk + (size_t)h * DD * HS;
    const float* WvH = Wv + (size_t)h * DD * HS;

    float aq[16], ak[16], av[16];
#pragma unroll
    for (int j = 0; j < 16; ++j) { aq[j] = 0.f; ak[j] = 0.f; av[j] = 0.f; }

    for (int kt = 0; kt < 8; ++kt) {
#pragma unroll
        for (int m = 0; m < 16; ++m) {
            int e = t + m * 256;
            int r = e >> 6, c = e & 63;
            Xs[r*64+c] = X[(size_t)(l0 + r) * DD + kt * 64 + c];
            W0[r*64+c] = WqH[(size_t)(kt * 64 + r) * HS + c];
            W1[r*64+c] = WkH[(size_t)(kt * 64 + r) * HS + c];
            W2[r*64+c] = WvH[(size_t)(kt * 64 + r) * HS + c];
        }
        __syncthreads();
        for (int kk = 0; kk < 64; ++kk) {
            float wq = W0[kk*64+col], wk = W1[kk*64+col], wv = W2[kk*64+col];
#pragma unroll
            for (int j = 0; j < 16; ++j) {
                float x = Xs[(w*16+j)*64 + kk];
                aq[j] = fmaf(x, wq, aq[j]);
                ak[j] = fmaf(x, wk, ak[j]);
                av[j] = fmaf(x, wv, av[j]);
            }
        }
        __syncthreads();
    }

    // xPos rotation: pairs (2i, 2i+1); partner value lives in lane col^1
    const int i2 = col >> 1;
#pragma unroll
    for (int j = 0; j < 16; ++j) {
        int r = w * 16 + j;
        int pos = l0 + r;
        float cq = tab[(size_t)pos * HALF + i2];
        float sq = tab[LQ*HALF + (size_t)pos * HALF + i2];
        float ck = tab[2*LQ*HALF + (size_t)pos * HALF + i2];
        float sk = tab[3*LQ*HALF + (size_t)pos * HALF + i2];
        float pq = __shfl_xor(aq[j], 1);
        float pk = __shfl_xor(ak[j], 1);
        float rq = (col & 1) ? pq : -pq;
        float rk = (col & 1) ? pk : -pk;
        size_t o = ((size_t)h * LQ + pos) * HS + col;
        q[o] = fmaf(aq[j], cq, rq * sq);
        float kv = fmaf(ak[j], ck, rk * sk);
        u16 khb = f2bf(kv);
        kh[o] = khb;
        kl[o] = f2bf(kv - bf2f(khb));
    }

    // v transpose via LDS (reuse smem as [64][65] floats)
    __syncthreads();
#pragma unroll
    for (int j = 0; j < 16; ++j) smem[col * 65 + w * 16 + j] = av[j];
    __syncthreads();
#pragma unroll
    for (int m = 0; m < 16; ++m) {
        int e = t + m * 256;
        int r = e >> 6, cc = e & 63;
        vt[((size_t)h * HS + r) * LQ + l0 + cc] = f2bf(smem[r * 65 + cc]);
    }
}

// ---------------- retention: MFMA flash-style causal with decay ----------------
// grid (64, 8), block 256 (4 waves). wave = (strip = i-rows 32, jh = j-half 32)
// ret layout: [l][h*64 + c] fp32
__global__ __launch_bounds__(256) void k_ret(
    const float* __restrict__ q, const u16* __restrict__ kh, const u16* __restrict__ kl,
    const u16* __restrict__ vt, float* __restrict__ ret) {
    __shared__ u16 sKH[4096], sKL[4096], sVT[4096], sS[4096];   // 8KB each, 64 rows x 128B, XOR-swizzled
    const int t = threadIdx.x;
    const int bx = blockIdx.x;
    const int qb = (bx & 1) ? (63 - (bx >> 1)) : (bx >> 1);     // load-balance pairing
    const int h = blockIdx.y;
    const int l0q = qb * 64;
    const int wv = t >> 6;
    const int lane = t & 63;
    const int c31 = lane & 31;
    const int hi = lane >> 5;
    const int strip = wv >> 1;   // i-rows strip*32..+31
    const int jh = wv & 1;       // j-cols jh*32..+31

    // decay constants (double precision)
    double lg = -3.4657359027997265 + (double)h * (-2.772588722239781 / 7.0);
    double gamma = 1.0 - exp(lg);
    float lgf = (float)(log(gamma) * 1.4426950408889634);   // log2(gamma) < 0
    float c1a[4], c8a[4];
#pragma unroll
    for (int m = 0; m < 4; ++m) { c1a[m] = exp2f(-lgf * (float)m); c8a[m] = exp2f(-lgf * (float)(8 * m)); }

    // Q fragments (B-operand): col i = c31, k(d) = 16*ks + 8*hi + jj ; fp32 -> hi/lo bf16
    s8v qhf[4], qlf[4];
    {
        const float* qp = q + ((size_t)h * LQ + l0q + strip * 32 + c31) * HS + hi * 8;
#pragma unroll
        for (int ks = 0; ks < 4; ++ks) {
            f4v a = *(const f4v*)(qp + ks * 16);
            f4v b = *(const f4v*)(qp + ks * 16 + 4);
            s8v qh, ql;
#pragma unroll
            for (int j = 0; j < 4; ++j) {
                u16 hb = f2bf(a[j]);
                qh[j] = (short)hb; ql[j] = (short)f2bf(a[j] - bf2f(hb));
                u16 hb2 = f2bf(b[j]);
                qh[j+4] = (short)hb2; ql[j+4] = (short)f2bf(b[j] - bf2f(hb2));
            }
            qhf[ks] = qh; qlf[ks] = ql;
        }
    }

    f16v oa0, oa1;
#pragma unroll
    for (int i = 0; i < 16; ++i) { oa0[i] = 0.f; oa1[i] = 0.f; }

    // decay-window tile skip: weights < 2^-80 are numerically nothing
    float dcut = -80.f / lgf;
    int kb_min = (int)floorf(((float)(l0q - 63) - dcut) * (1.f / 64.f));
    if (kb_min < 0) kb_min = 0;

    const int srow = strip * 32 + c31;

    for (int kb = kb_min; kb <= qb; ++kb) {
        // ---- stage K_hi, K_lo, VT (8KB each), linear global read -> swizzled LDS write ----
        {
            const char* gkh = (const char*)(kh + ((size_t)h * LQ + kb * 64) * HS);
            const char* gkl = (const char*)(kl + ((size_t)h * LQ + kb * 64) * HS);
#pragma unroll
            for (int it = 0; it < 2; ++it) {
                int o = t * 16 + it * 4096;
                int sw = o ^ (((o >> 7) & 7) << 4);
                *(s8v*)((char*)sKH + sw) = *(const s8v*)(gkh + o);
                *(s8v*)((char*)sKL + sw) = *(const s8v*)(gkl + o);
                int r = o >> 7, cbyte = o & 127;
                const char* gv = (const char*)(vt + ((size_t)h * HS + r) * LQ + kb * 64);
                *(s8v*)((char*)sVT + sw) = *(const s8v*)(gv + cbyte);
            }
        }
        __syncthreads();

        const bool diag = (kb == qb);
        if (!(diag && strip < jh)) {
            // ---- QK^T: S'[j][i] = mfma(A=K rows, B=Q^T), 3-way hi/lo split ----
            f16v sacc;
#pragma unroll
            for (int i = 0; i < 16; ++i) sacc[i] = 0.f;
            const int krow = jh * 32 + c31;
            const int kswz = (krow & 7) << 4;
#pragma unroll
            for (int ks = 0; ks < 4; ++ks) {
                int cb = 32 * ks + 16 * hi;
                int ph = krow * 128 + (cb ^ kswz);
                s8v ah = *(const s8v*)((const char*)sKH + ph);
                s8v al = *(const s8v*)((const char*)sKL + ph);
                sacc = __builtin_amdgcn_mfma_f32_32x32x16_bf16(ah, qhf[ks], sacc, 0, 0, 0);
                sacc = __builtin_amdgcn_mfma_f32_32x32x16_bf16(ah, qlf[ks], sacc, 0, 0, 0);
                sacc = __builtin_amdgcn_mfma_f32_32x32x16_bf16(al, qhf[ks], sacc, 0, 0, 0);
            }
            // ---- decay + pack to S (bf16, swizzled LDS, wave-private quadrant) ----
            const int D0 = (l0q + strip * 32 + c31) - (kb * 64 + jh * 32);
            float base = exp2f(lgf * (float)(D0 - 4 * hi));
            const int sswz = (srow & 7) << 4;
#pragma unroll
            for (int g = 0; g < 4; ++g) {
                float wg = base * c8a[g];
                u16 p[4];
#pragma unroll
                for (int m = 0; m < 4; ++m) {
                    float val = sacc[4 * g + m] * (wg * c1a[m]);
                    if (diag) { int di = D0 - (m + 8 * g + 4 * hi); if (di < 0) val = 0.f; }
                    p[m] = f2bf(val);
                }
                int cb = jh * 64 + 16 * g + 8 * hi;
                int ph = srow * 128 + (cb ^ sswz);
                unsigned long long pk = (unsigned long long)p[0] | ((unsigned long long)p[1] << 16)
                                      | ((unsigned long long)p[2] << 32) | ((unsigned long long)p[3] << 48);
                *(unsigned long long*)((char*)sS + ph) = pk;
            }
            // ---- PV: O[i][c] += S[i][j] * V[j][c]  (A=S rows, B=VT rows) ----
#pragma unroll
            for (int ks = 0; ks < 2; ++ks) {
                int cb = jh * 64 + 32 * ks + 16 * hi;
                s8v sa = *(const s8v*)((const char*)sS + srow * 128 + (cb ^ sswz));
                int rv0 = c31;
                s8v vb0 = *(const s8v*)((const char*)sVT + rv0 * 128 + (cb ^ ((rv0 & 7) << 4)));
                oa0 = __builtin_amdgcn_mfma_f32_32x32x16_bf16(sa, vb0, oa0, 0, 0, 0);
                int rv1 = 32 + c31;
                s8v vb1 = *(const s8v*)((const char*)sVT + rv1 * 128 + (cb ^ ((rv1 & 7) << 4)));
                oa1 = __builtin_amdgcn_mfma_f32_32x32x16_bf16(sa, vb1, oa1, 0, 0, 0);
            }
        }
        __syncthreads();
    }

    // ---- reduce partial O across jh pairs (LDS), then store ----
    __syncthreads();
    float* red = (float*)(strip ? (void*)sKL : (void*)sKH);   // 8KB: [32][64] fp32
    if (jh == 1) {
#pragma unroll
        for (int r = 0; r < 16; ++r) {
            int irow = (r & 3) + 8 * (r >> 2) + 4 * hi;
            red[irow * 64 + c31]      = oa0[r];
            red[irow * 64 + 32 + c31] = oa1[r];
        }
    }
    __syncthreads();
    if (jh == 0) {
#pragma unroll
        for (int r = 0; r < 16; ++r) {
            int irow = (r & 3) + 8 * (r >> 2) + 4 * hi;
            size_t o = (size_t)(l0q + strip * 32 + irow) * DD + h * HS;
            ret[o + c31]      = oa0[r] + red[irow * 64 + c31];
            ret[o + 32 + c31] = oa1[r] + red[irow * 64 + 32 + c31];
        }
    }
}

// ---------------- generic 64x64-tiled matmul (LxD @ DxD), optional silu ----------------
__global__ __launch_bounds__(256) void k_mm(
    const float* __restrict__ A, const float* __restrict__ W,
    float* __restrict__ out, int do_silu) {
    __shared__ float As[64][65];
    __shared__ float Ws[64][64];
    const int t = threadIdx.x;
    const int l0 = blockIdx.x * 64;
    const int c0 = blockIdx.y * 64;
    const int tr = t >> 4, tc = t & 15;

    float acc[4][4];
#pragma unroll
    for (int i = 0; i < 4; ++i)
#pragma unroll
        for (int j = 0; j < 4; ++j) acc[i][j] = 0.f;

    for (int kt = 0; kt < 8; ++kt) {
#pragma unroll
        for (int m = 0; m < 16; ++m) {
            int e = t + m * 256;
            int r = e >> 6, c = e & 63;
            As[r][c] = A[(size_t)(l0 + r) * DD + kt * 64 + c];
            Ws[r][c] = W[(size_t)(kt * 64 + r) * DD + c0 + c];
        }
        __syncthreads();
        for (int kk = 0; kk < 64; ++kk) {
            float xv[4], wv[4];
#pragma unroll
            for (int i = 0; i < 4; ++i) xv[i] = As[tr * 4 + i][kk];
#pragma unroll
            for (int j = 0; j < 4; ++j) wv[j] = Ws[kk][tc * 4 + j];
#pragma unroll
            for (int i = 0; i < 4; ++i)
#pragma unroll
                for (int j = 0; j < 4; ++j) acc[i][j] = fmaf(xv[i], wv[j], acc[i][j]);
        }
        __syncthreads();
    }

#pragma unroll
    for (int i = 0; i < 4; ++i) {
#pragma unroll
        for (int j = 0; j < 4; ++j) {
            float a = acc[i][j];
            if (do_silu) a = a / (1.f + expf(-a));
            out[(size_t)(l0 + tr * 4 + i) * DD + c0 + tc * 4 + j] = a;
        }
    }
}

// ---------------- GroupNorm (per l,h over 64 channels) * gate, in place on ret ----------------
__global__ __launch_bounds__(256) void k_gn(
    float* __restrict__ ret, const float* __restrict__ gate,
    const float* __restrict__ gw, const float* __restrict__ gb) {
    const int t = threadIdx.x;
    const int w = t >> 6;
    const int lane = t & 63;
    const int grp = blockIdx.x * 4 + w;
    const int l = grp >> 3;
    const int h = grp & 7;
    const size_t idx = (size_t)l * DD + h * HS + lane;

    float val = ret[idx];
    float s = val;
#pragma unroll
    for (int off = 1; off < 64; off <<= 1) s += __shfl_xor(s, off);
    float mean = s * (1.f / 64.f);
    float d = val - mean;
    float ss = d * d;
#pragma unroll
    for (int off = 1; off < 64; off <<= 1) ss += __shfl_xor(ss, off);
    float var = ss * (1.f / 64.f);
    float g = d * rsqrtf(var + 1e-5f);
    g = fmaf(g, gw[h * HS + lane], gb[h * HS + lane]);
    ret[idx] = g * gate[idx];
}

extern "C" void kernel_launch(void* const* d_in, const int* in_sizes, int n_in,
                              void* d_out, int out_size, void* d_ws, size_t ws_size,
                              hipStream_t stream) {
    const float* X   = (const float*)d_in[0];
    const float* W_Q = (const float*)d_in[1];
    const float* W_K = (const float*)d_in[2];
    const float* W_V = (const float*)d_in[3];
    const float* W_G = (const float*)d_in[4];
    const float* W_O = (const float*)d_in[5];
    const float* gnw = (const float*)d_in[6];
    const float* gnb = (const float*)d_in[7];

    float* ws   = (float*)d_ws;
    float* q    = ws + WS_Q;
    u16*   kh   = (u16*)(ws + WS_KH);
    u16*   kl   = (u16*)(ws + WS_KL);
    u16*   vt   = (u16*)(ws + WS_VT);
    float* ret  = ws + WS_RET;
    float* gate = ws + WS_GATE;
    float* tab  = ws + WS_TAB;
    float* out  = (float*)d_out;

    k_tables<<<(LQ * HALF + 255) / 256, 256, 0, stream>>>(tab);
    k_qkv<<<dim3(LQ / 64, NH), 256, 0, stream>>>(X, W_Q, W_K, W_V, tab, q, kh, kl, vt);
    k_ret<<<dim3(LQ / 64, NH), 256, 0, stream>>>(q, kh, kl, vt, ret);
    k_mm<<<dim3(LQ / 64, DD / 64), 256, 0, stream>>>(X, W_G, gate, 1);
    k_gn<<<(LQ * NH) / 4, 256, 0, stream>>>(ret, gate, gnw, gnb);
    k_mm<<<dim3(LQ / 64, DD / 64), 256, 0, stream>>>(ret, W_O, out, 0);
}

// Round 3
// 167.100 us; speedup vs baseline: 5.4088x; 2.3304x over previous
//
#include <hip/hip_runtime.h>
#include <math.h>

#define LQ 4096
#define DD 512
#define NH 8
#define HS 64
#define HALF 32

typedef unsigned short u16;
typedef __attribute__((ext_vector_type(8)))  short s8v;   // 8 x bf16 (MFMA A/B frag)
typedef __attribute__((ext_vector_type(4)))  float f4v;
typedef __attribute__((ext_vector_type(16))) float f16v;  // 32x32 MFMA C/D

// workspace offsets (in floats)
#define WS_QH   0u          // later reused as gg_hi
#define WS_QL   1048576u    // later reused as gg_lo
#define WS_KH   2097152u
#define WS_KL   3145728u
#define WS_VT   4194304u
#define WS_XH   5242880u    // later reused as ret (spans XH+XL = 2097152 floats)
#define WS_XL   6291456u
#define WS_WTH  7340032u    // 2560*512 u16 = 655360 float slots
#define WS_WTL  7995392u
#define WS_GATE 8650752u    // 2097152 floats
#define WS_TAB  10747904u   // 524288 floats

__device__ inline u16 f2bf(float x) {
    unsigned int u = __float_as_uint(x);
    return (u16)((u + 0x7fffu + ((u >> 16) & 1u)) >> 16);
}
__device__ inline float bf2f(u16 h) { return __uint_as_float(((unsigned int)h) << 16); }

// ---------------- xPos tables (double precision, tiny) ----------------
__global__ __launch_bounds__(256) void k_tables(float* __restrict__ tab) {
    int idx = blockIdx.x * 256 + threadIdx.x;   // LQ*HALF = 131072
    if (idx >= LQ * HALF) return;
    int l = idx >> 5;
    int i = idx & 31;
    double sv  = (2.0 * i + 0.4 * (double)HS) / (1.4 * (double)HS);
    double s   = pow(sv, (double)l / 512.0);
    double invf = pow(10000.0, -(double)i / (double)HALF);
    double th  = (double)l * invf;
    double c = cos(th), sn = sin(th);
    tab[idx]                 = (float)(c * s);
    tab[LQ*HALF + idx]       = (float)(sn * s);
    tab[2*LQ*HALF + idx]     = (float)(c / s);
    tab[3*LQ*HALF + idx]     = (float)(sn / s);
}

// ---------------- weight transpose-pack: Wt[C][d] hi/lo bf16, C in [q|k|v|g|o] ----------------
// grid (16 d-tiles, 80 c-tiles), block 256
__global__ __launch_bounds__(256) void k_prep(
    const float* __restrict__ Wq, const float* __restrict__ Wk, const float* __restrict__ Wv,
    const float* __restrict__ Wg, const float* __restrict__ Wo,
    u16* __restrict__ Wth, u16* __restrict__ Wtl) {
    __shared__ float tile[32][33];
    const int t = threadIdx.x;
    const int d0 = blockIdx.x * 32;
    const int C0 = blockIdx.y * 32;
    const int proj = C0 >> 9;
    const int tc = t & 31;
    const int tr = t >> 5;   // 0..7
#pragma unroll
    for (int rr = 0; rr < 4; ++rr) {
        int dl = tr + rr * 8;
        int d = d0 + dl;
        int C = C0 + tc;
        float val;
        if (proj < 3) {
            const float* W = (proj == 0) ? Wq : ((proj == 1) ? Wk : Wv);
            int h = (C & 511) >> 6, hs = C & 63;
            val = W[(size_t)h * (DD * HS) + (size_t)d * HS + hs];
        } else if (proj == 3) {
            val = Wg[(size_t)d * DD + (C & 511)];
        } else {
            val = Wo[(size_t)d * DD + (C - 2048)];
        }
        tile[dl][tc] = val;
    }
    __syncthreads();
#pragma unroll
    for (int rr = 0; rr < 4; ++rr) {
        int cl = tr + rr * 8;
        float val = tile[tc][cl];
        u16 hb = f2bf(val);
        size_t o = (size_t)(C0 + cl) * DD + d0 + tc;
        Wth[o] = hb;
        Wtl[o] = f2bf(val - bf2f(hb));
    }
}

// ---------------- X -> hi/lo bf16 ----------------
__global__ __launch_bounds__(256) void k_packx(const float* __restrict__ X,
                                               u16* __restrict__ Xh, u16* __restrict__ Xl) {
    int idx = (blockIdx.x * 256 + threadIdx.x) * 4;
    f4v x = *(const f4v*)(X + idx);
    unsigned int h[4], l[4];
#pragma unroll
    for (int j = 0; j < 4; ++j) {
        u16 hb = f2bf(x[j]);
        h[j] = hb;
        l[j] = f2bf(x[j] - bf2f(hb));
    }
    uint2 ph, pl;
    ph.x = h[0] | (h[1] << 16); ph.y = h[2] | (h[3] << 16);
    pl.x = l[0] | (l[1] << 16); pl.y = l[2] | (l[3] << 16);
    *(uint2*)((void*)(Xh + idx)) = ph;
    *(uint2*)((void*)(Xl + idx)) = pl;
}

// ---------------- fused MFMA GEMM: X @ [Wq|Wk|Wv|Wg] with per-proj epilogue ----------------
// grid (32 l-tiles of 128, 32 c-tiles of 64), block 256 (4 waves, each 32l x 64c)
__global__ __launch_bounds__(256) void k_fused(
    const u16* __restrict__ Xh, const u16* __restrict__ Xl,
    const u16* __restrict__ Wth, const u16* __restrict__ Wtl,
    const float* __restrict__ tab,
    u16* __restrict__ qh, u16* __restrict__ ql,
    u16* __restrict__ kh, u16* __restrict__ kl,
    u16* __restrict__ vt, float* __restrict__ gate) {
    __shared__ __align__(16) char smem[49152];
    char* sAH = smem;            // 16KB: 128 rows x 128B, swizzled
    char* sAL = smem + 16384;    // 16KB
    char* sBH = smem + 32768;    // 8KB: 64 rows x 128B
    char* sBL = smem + 40960;    // 8KB
    const int t = threadIdx.x;
    const int l0 = blockIdx.x * 128;
    const int c0 = blockIdx.y * 64;
    const int wv = t >> 6;
    const int lane = t & 63;
    const int c31 = lane & 31;
    const int hi = lane >> 5;

    f16v acc0, acc1;
#pragma unroll
    for (int i = 0; i < 16; ++i) { acc0[i] = 0.f; acc1[i] = 0.f; }

    for (int kt = 0; kt < 8; ++kt) {
#pragma unroll
        for (int it = 0; it < 4; ++it) {
            int o = t * 16 + it * 4096;
            int row = o >> 7, cb = o & 127;
            int sw = o ^ ((row & 7) << 4);
            size_t g = (size_t)(l0 + row) * 1024 + kt * 128 + cb;
            *(s8v*)(sAH + sw) = *(const s8v*)((const char*)Xh + g);
            *(s8v*)(sAL + sw) = *(const s8v*)((const char*)Xl + g);
        }
#pragma unroll
        for (int it = 0; it < 2; ++it) {
            int o = t * 16 + it * 4096;
            int row = o >> 7, cb = o & 127;
            int sw = o ^ ((row & 7) << 4);
            size_t g = (size_t)(c0 + row) * 1024 + kt * 128 + cb;
            *(s8v*)(sBH + sw) = *(const s8v*)((const char*)Wth + g);
            *(s8v*)(sBL + sw) = *(const s8v*)((const char*)Wtl + g);
        }
        __syncthreads();

        const int arow = wv * 32 + c31;
        const int aswz = (arow & 7) << 4;
        s8v ah[4], al[4];
#pragma unroll
        for (int ks = 0; ks < 4; ++ks) {
            int cb = (ks * 32 + hi * 16) ^ aswz;
            ah[ks] = *(const s8v*)(sAH + arow * 128 + cb);
            al[ks] = *(const s8v*)(sAL + arow * 128 + cb);
        }
#define DO_N(NN, ACC)                                                              \
        {                                                                          \
            int brow = NN * 32 + c31;                                              \
            int bswz = (brow & 7) << 4;                                            \
            _Pragma("unroll")                                                      \
            for (int ks = 0; ks < 4; ++ks) {                                       \
                int cb = (ks * 32 + hi * 16) ^ bswz;                               \
                s8v bh = *(const s8v*)(sBH + brow * 128 + cb);                     \
                s8v bl = *(const s8v*)(sBL + brow * 128 + cb);                     \
                ACC = __builtin_amdgcn_mfma_f32_32x32x16_bf16(ah[ks], bh, ACC, 0, 0, 0); \
                ACC = __builtin_amdgcn_mfma_f32_32x32x16_bf16(ah[ks], bl, ACC, 0, 0, 0); \
                ACC = __builtin_amdgcn_mfma_f32_32x32x16_bf16(al[ks], bh, ACC, 0, 0, 0); \
            }                                                                      \
        }
        DO_N(0, acc0)
        DO_N(1, acc1)
#undef DO_N
        __syncthreads();
    }

    const int proj = c0 >> 9;
    if (proj < 2) {
        const float* ct = tab + (proj ? 2 * LQ * HALF : 0);
        const float* st = tab + (proj ? 3 * LQ * HALF : LQ * HALF);
        u16* oh = proj ? kh : qh;
        u16* ol = proj ? kl : ql;
#pragma unroll
        for (int n = 0; n < 2; ++n) {
            const f16v acc = n ? acc1 : acc0;
            int C = c0 + n * 32 + c31;
            int h = (C & 511) >> 6, hs = C & 63, i2 = hs >> 1;
            float sgn = (hs & 1) ? 1.f : -1.f;
#pragma unroll
            for (int r = 0; r < 16; ++r) {
                int lrow = wv * 32 + (r & 3) + 8 * (r >> 2) + 4 * hi;
                int pos = l0 + lrow;
                float val = acc[r];
                float part = __shfl_xor(val, 1);
                float res = val * ct[pos * HALF + i2] + sgn * part * st[pos * HALF + i2];
                u16 hb = f2bf(res);
                size_t o = ((size_t)h * LQ + pos) * HS + hs;
                oh[o] = hb;
                ol[o] = f2bf(res - bf2f(hb));
            }
        }
    } else if (proj == 2) {
        __syncthreads();                      // all frag reads done before overwrite
        float* vbuf = (float*)smem;           // [64][129] f32 = 33KB
#pragma unroll
        for (int n = 0; n < 2; ++n) {
            const f16v acc = n ? acc1 : acc0;
            int cl = n * 32 + c31;
#pragma unroll
            for (int r = 0; r < 16; ++r) {
                int lrow = wv * 32 + (r & 3) + 8 * (r >> 2) + 4 * hi;
                vbuf[cl * 129 + lrow] = acc[r];
            }
        }
        __syncthreads();
        int h = (c0 & 511) >> 6;
        int cl = t >> 2, lseg = (t & 3) * 32;
        size_t o = ((size_t)h * HS + cl) * LQ + l0 + lseg;
#pragma unroll
        for (int ch = 0; ch < 4; ++ch) {
            s8v pk;
#pragma unroll
            for (int j = 0; j < 8; ++j) pk[j] = (short)f2bf(vbuf[cl * 129 + lseg + ch * 8 + j]);
            *(s8v*)(vt + o + ch * 8) = pk;
        }
    } else {
#pragma unroll
        for (int n = 0; n < 2; ++n) {
            const f16v acc = n ? acc1 : acc0;
            int C = (c0 & 511) + n * 32 + c31;
#pragma unroll
            for (int r = 0; r < 16; ++r) {
                int lrow = wv * 32 + (r & 3) + 8 * (r >> 2) + 4 * hi;
                float vv = acc[r];
                gate[(size_t)(l0 + lrow) * DD + C] = vv / (1.f + expf(-vv));
            }
        }
    }
}

// ---------------- retention: MFMA flash-style causal with decay ----------------
// grid (64, 8), block 256 (4 waves). ret layout: [l][h*64 + c] fp32
__global__ __launch_bounds__(256) void k_ret(
    const u16* __restrict__ qh, const u16* __restrict__ ql,
    const u16* __restrict__ kh, const u16* __restrict__ kl,
    const u16* __restrict__ vt, float* __restrict__ ret) {
    __shared__ u16 sKH[4096], sKL[4096], sVT[4096], sS[4096];
    const int t = threadIdx.x;
    const int bx = blockIdx.x;
    const int qb = (bx & 1) ? (63 - (bx >> 1)) : (bx >> 1);
    const int h = blockIdx.y;
    const int l0q = qb * 64;
    const int wv = t >> 6;
    const int lane = t & 63;
    const int c31 = lane & 31;
    const int hi = lane >> 5;
    const int strip = wv >> 1;
    const int jh = wv & 1;

    double lg = -3.4657359027997265 + (double)h * (-2.772588722239781 / 7.0);
    double gamma = 1.0 - exp(lg);
    float lgf = (float)(log(gamma) * 1.4426950408889634);
    float c1a[4], c8a[4];
#pragma unroll
    for (int m = 0; m < 4; ++m) { c1a[m] = exp2f(-lgf * (float)m); c8a[m] = exp2f(-lgf * (float)(8 * m)); }

    s8v qhf[4], qlf[4];
    {
        const u16* qph = qh + ((size_t)h * LQ + l0q + strip * 32 + c31) * HS + hi * 8;
        const u16* qpl = ql + ((size_t)h * LQ + l0q + strip * 32 + c31) * HS + hi * 8;
#pragma unroll
        for (int ks = 0; ks < 4; ++ks) {
            qhf[ks] = *(const s8v*)(qph + ks * 16);
            qlf[ks] = *(const s8v*)(qpl + ks * 16);
        }
    }

    f16v oa0, oa1;
#pragma unroll
    for (int i = 0; i < 16; ++i) { oa0[i] = 0.f; oa1[i] = 0.f; }

    float dcut = -80.f / lgf;
    int kb_min = (int)floorf(((float)(l0q - 63) - dcut) * (1.f / 64.f));
    if (kb_min < 0) kb_min = 0;

    const int srow = strip * 32 + c31;

    for (int kb = kb_min; kb <= qb; ++kb) {
        {
            const char* gkh = (const char*)(kh + ((size_t)h * LQ + kb * 64) * HS);
            const char* gkl = (const char*)(kl + ((size_t)h * LQ + kb * 64) * HS);
#pragma unroll
            for (int it = 0; it < 2; ++it) {
                int o = t * 16 + it * 4096;
                int sw = o ^ (((o >> 7) & 7) << 4);
                *(s8v*)((char*)sKH + sw) = *(const s8v*)(gkh + o);
                *(s8v*)((char*)sKL + sw) = *(const s8v*)(gkl + o);
                int r = o >> 7, cbyte = o & 127;
                const char* gv = (const char*)(vt + ((size_t)h * HS + r) * LQ + kb * 64);
                *(s8v*)((char*)sVT + sw) = *(const s8v*)(gv + cbyte);
            }
        }
        __syncthreads();

        const bool diag = (kb == qb);
        if (!(diag && strip < jh)) {
            f16v sacc;
#pragma unroll
            for (int i = 0; i < 16; ++i) sacc[i] = 0.f;
            const int krow = jh * 32 + c31;
            const int kswz = (krow & 7) << 4;
#pragma unroll
            for (int ks = 0; ks < 4; ++ks) {
                int cb = 32 * ks + 16 * hi;
                int ph = krow * 128 + (cb ^ kswz);
                s8v ah = *(const s8v*)((const char*)sKH + ph);
                s8v al = *(const s8v*)((const char*)sKL + ph);
                sacc = __builtin_amdgcn_mfma_f32_32x32x16_bf16(ah, qhf[ks], sacc, 0, 0, 0);
                sacc = __builtin_amdgcn_mfma_f32_32x32x16_bf16(ah, qlf[ks], sacc, 0, 0, 0);
                sacc = __builtin_amdgcn_mfma_f32_32x32x16_bf16(al, qhf[ks], sacc, 0, 0, 0);
            }
            const int D0 = (l0q + strip * 32 + c31) - (kb * 64 + jh * 32);
            float base = exp2f(lgf * (float)(D0 - 4 * hi));
            const int sswz = (srow & 7) << 4;
#pragma unroll
            for (int g = 0; g < 4; ++g) {
                float wg = base * c8a[g];
                u16 p[4];
#pragma unroll
                for (int m = 0; m < 4; ++m) {
                    float val = sacc[4 * g + m] * (wg * c1a[m]);
                    if (diag) { int di = D0 - (m + 8 * g + 4 * hi); if (di < 0) val = 0.f; }
                    p[m] = f2bf(val);
                }
                int cb = jh * 64 + 16 * g + 8 * hi;
                int ph = srow * 128 + (cb ^ sswz);
                unsigned long long pk = (unsigned long long)p[0] | ((unsigned long long)p[1] << 16)
                                      | ((unsigned long long)p[2] << 32) | ((unsigned long long)p[3] << 48);
                *(unsigned long long*)((char*)sS + ph) = pk;
            }
#pragma unroll
            for (int ks = 0; ks < 2; ++ks) {
                int cb = jh * 64 + 32 * ks + 16 * hi;
                s8v sa = *(const s8v*)((const char*)sS + srow * 128 + (cb ^ sswz));
                int rv0 = c31;
                s8v vb0 = *(const s8v*)((const char*)sVT + rv0 * 128 + (cb ^ ((rv0 & 7) << 4)));
                oa0 = __builtin_amdgcn_mfma_f32_32x32x16_bf16(sa, vb0, oa0, 0, 0, 0);
                int rv1 = 32 + c31;
                s8v vb1 = *(const s8v*)((const char*)sVT + rv1 * 128 + (cb ^ ((rv1 & 7) << 4)));
                oa1 = __builtin_amdgcn_mfma_f32_32x32x16_bf16(sa, vb1, oa1, 0, 0, 0);
            }
        }
        __syncthreads();
    }

    __syncthreads();
    float* red = (float*)(strip ? (void*)sKL : (void*)sKH);
    if (jh == 1) {
#pragma unroll
        for (int r = 0; r < 16; ++r) {
            int irow = (r & 3) + 8 * (r >> 2) + 4 * hi;
            red[irow * 64 + c31]      = oa0[r];
            red[irow * 64 + 32 + c31] = oa1[r];
        }
    }
    __syncthreads();
    if (jh == 0) {
#pragma unroll
        for (int r = 0; r < 16; ++r) {
            int irow = (r & 3) + 8 * (r >> 2) + 4 * hi;
            size_t o = (size_t)(l0q + strip * 32 + irow) * DD + h * HS;
            ret[o + c31]      = oa0[r] + red[irow * 64 + c31];
            ret[o + 32 + c31] = oa1[r] + red[irow * 64 + 32 + c31];
        }
    }
}

// ---------------- GroupNorm * gate -> gg hi/lo bf16 ----------------
__global__ __launch_bounds__(256) void k_gn(
    const float* __restrict__ ret, const float* __restrict__ gate,
    const float* __restrict__ gw, const float* __restrict__ gb,
    u16* __restrict__ ggh, u16* __restrict__ ggl) {
    const int t = threadIdx.x;
    const int w = t >> 6;
    const int lane = t & 63;
    const int grp = blockIdx.x * 4 + w;
    const int l = grp >> 3;
    const int h = grp & 7;
    const size_t idx = (size_t)l * DD + h * HS + lane;

    float val = ret[idx];
    float s = val;
#pragma unroll
    for (int off = 1; off < 64; off <<= 1) s += __shfl_xor(s, off);
    float mean = s * (1.f / 64.f);
    float d = val - mean;
    float ss = d * d;
#pragma unroll
    for (int off = 1; off < 64; off <<= 1) ss += __shfl_xor(ss, off);
    float var = ss * (1.f / 64.f);
    float g = d * rsqrtf(var + 1e-5f);
    g = fmaf(g, gw[h * HS + lane], gb[h * HS + lane]);
    float vv = g * gate[idx];
    u16 hb = f2bf(vv);
    ggh[idx] = hb;
    ggl[idx] = f2bf(vv - bf2f(hb));
}

// ---------------- out = gg @ W_O  (MFMA, hi/lo) ----------------
// grid (32 l-tiles of 128, 8 c-tiles of 64), block 256
__global__ __launch_bounds__(256) void k_out(
    const u16* __restrict__ Ah, const u16* __restrict__ Al,
    const u16* __restrict__ Wth, const u16* __restrict__ Wtl,
    float* __restrict__ out) {
    __shared__ __align__(16) char smem[49152];
    char* sAH = smem;
    char* sAL = smem + 16384;
    char* sBH = smem + 32768;
    char* sBL = smem + 40960;
    const int t = threadIdx.x;
    const int l0 = blockIdx.x * 128;
    const int c0 = blockIdx.y * 64;
    const int wv = t >> 6;
    const int lane = t & 63;
    const int c31 = lane & 31;
    const int hi = lane >> 5;

    f16v acc0, acc1;
#pragma unroll
    for (int i = 0; i < 16; ++i) { acc0[i] = 0.f; acc1[i] = 0.f; }

    for (int kt = 0; kt < 8; ++kt) {
#pragma unroll
        for (int it = 0; it < 4; ++it) {
            int o = t * 16 + it * 4096;
            int row = o >> 7, cb = o & 127;
            int sw = o ^ ((row & 7) << 4);
            size_t g = (size_t)(l0 + row) * 1024 + kt * 128 + cb;
            *(s8v*)(sAH + sw) = *(const s8v*)((const char*)Ah + g);
            *(s8v*)(sAL + sw) = *(const s8v*)((const char*)Al + g);
        }
#pragma unroll
        for (int it = 0; it < 2; ++it) {
            int o = t * 16 + it * 4096;
            int row = o >> 7, cb = o & 127;
            int sw = o ^ ((row & 7) << 4);
            size_t g = (size_t)(2048 + c0 + row) * 1024 + kt * 128 + cb;
            *(s8v*)(sBH + sw) = *(const s8v*)((const char*)Wth + g);
            *(s8v*)(sBL + sw) = *(const s8v*)((const char*)Wtl + g);
        }
        __syncthreads();

        const int arow = wv * 32 + c31;
        const int aswz = (arow & 7) << 4;
        s8v ah[4], al[4];
#pragma unroll
        for (int ks = 0; ks < 4; ++ks) {
            int cb = (ks * 32 + hi * 16) ^ aswz;
            ah[ks] = *(const s8v*)(sAH + arow * 128 + cb);
            al[ks] = *(const s8v*)(sAL + arow * 128 + cb);
        }
#define DO_N(NN, ACC)                                                              \
        {                                                                          \
            int brow = NN * 32 + c31;                                              \
            int bswz = (brow & 7) << 4;                                            \
            _Pragma("unroll")                                                      \
            for (int ks = 0; ks < 4; ++ks) {                                       \
                int cb = (ks * 32 + hi * 16) ^ bswz;                               \
                s8v bh = *(const s8v*)(sBH + brow * 128 + cb);                     \
                s8v bl = *(const s8v*)(sBL + brow * 128 + cb);                     \
                ACC = __builtin_amdgcn_mfma_f32_32x32x16_bf16(ah[ks], bh, ACC, 0, 0, 0); \
                ACC = __builtin_amdgcn_mfma_f32_32x32x16_bf16(ah[ks], bl, ACC, 0, 0, 0); \
                ACC = __builtin_amdgcn_mfma_f32_32x32x16_bf16(al[ks], bh, ACC, 0, 0, 0); \
            }                                                                      \
        }
        DO_N(0, acc0)
        DO_N(1, acc1)
#undef DO_N
        __syncthreads();
    }

#pragma unroll
    for (int n = 0; n < 2; ++n) {
        const f16v acc = n ? acc1 : acc0;
        int C = c0 + n * 32 + c31;
#pragma unroll
        for (int r = 0; r < 16; ++r) {
            int lrow = wv * 32 + (r & 3) + 8 * (r >> 2) + 4 * hi;
            out[(size_t)(l0 + lrow) * DD + C] = acc[r];
        }
    }
}

extern "C" void kernel_launch(void* const* d_in, const int* in_sizes, int n_in,
                              void* d_out, int out_size, void* d_ws, size_t ws_size,
                              hipStream_t stream) {
    const float* X   = (const float*)d_in[0];
    const float* W_Q = (const float*)d_in[1];
    const float* W_K = (const float*)d_in[2];
    const float* W_V = (const float*)d_in[3];
    const float* W_G = (const float*)d_in[4];
    const float* W_O = (const float*)d_in[5];
    const float* gnw = (const float*)d_in[6];
    const float* gnb = (const float*)d_in[7];

    float* ws   = (float*)d_ws;
    u16* qhp  = (u16*)(ws + WS_QH);
    u16* qlp  = (u16*)(ws + WS_QL);
    u16* khp  = (u16*)(ws + WS_KH);
    u16* klp  = (u16*)(ws + WS_KL);
    u16* vtp  = (u16*)(ws + WS_VT);
    u16* xhp  = (u16*)(ws + WS_XH);
    u16* xlp  = (u16*)(ws + WS_XL);
    u16* wth  = (u16*)(ws + WS_WTH);
    u16* wtl  = (u16*)(ws + WS_WTL);
    float* gate = ws + WS_GATE;
    float* tab  = ws + WS_TAB;
    float* ret  = ws + WS_XH;          // reuse X region after k_fused
    u16* ggh  = (u16*)(ws + WS_QH);    // reuse q region after k_ret
    u16* ggl  = (u16*)(ws + WS_QL);
    float* out  = (float*)d_out;

    k_tables<<<512, 256, 0, stream>>>(tab);
    k_packx<<<2048, 256, 0, stream>>>(X, xhp, xlp);
    k_prep<<<dim3(16, 80), 256, 0, stream>>>(W_Q, W_K, W_V, W_G, W_O, wth, wtl);
    k_fused<<<dim3(32, 32), 256, 0, stream>>>(xhp, xlp, wth, wtl, tab, qhp, qlp, khp, klp, vtp, gate);
    k_ret<<<dim3(64, 8), 256, 0, stream>>>(qhp, qlp, khp, klp, vtp, ret);
    k_gn<<<(LQ * NH) / 4, 256, 0, stream>>>(ret, gate, gnw, gnb, ggh, ggl);
    k_out<<<dim3(32, 8), 256, 0, stream>>>(ggh, ggl, wth, wtl, out);
}